// Round 1
// baseline (67.945 us; speedup 1.0000x reference)
//
#include <hip/hip_runtime.h>

// NCuts loss: seg [8,4,224,224], padded_seg [8,4,232,232],
// weight [8,1,224,224,9,9], sum_weight [8,1,224,224] -> out[8] (fp32)

constexpr int NN  = 8;
constexpr int KK  = 4;
constexpr int HH  = 224;
constexpr int WW  = 224;
constexpr int PAD = 4;                   // RADIUS-1
constexpr int HP  = HH + 2 * PAD;        // 232
constexpr int WP  = WW + 2 * PAD;        // 232
constexpr int WINN = 9;
constexpr int NWIN = 81;
constexpr int PIX = HH * WW;             // 50176
constexpr int TPB = 256;
constexpr int BPI = PIX / TPB;           // 196 (exact)
constexpr int PLANE = HP * WP;           // 53824

__global__ __launch_bounds__(TPB) void ncuts_stage1(
    const float* __restrict__ seg, const float* __restrict__ pseg,
    const float* __restrict__ wgt, const float* __restrict__ swgt,
    float* __restrict__ part)
{
    const int blk = blockIdx.x;
    const int n   = blk / BPI;
    const int bi  = blk - n * BPI;
    const int tid = threadIdx.x;
    const int p   = bi * TPB + tid;      // pixel within image, always < PIX
    const int h   = p / WW;
    const int w   = p - h * WW;

    const float* wp = wgt + ((size_t)n * PIX + p) * NWIN;
    const float* pb = pseg + (size_t)n * KK * PLANE + (size_t)h * WP + w;

    float acc0 = 0.f, acc1 = 0.f, acc2 = 0.f, acc3 = 0.f;
#pragma unroll
    for (int m = 0; m < WINN; ++m) {
        const float* pr = pb + m * WP;
#pragma unroll
        for (int j = 0; j < WINN; ++j) {
            const float wv = wp[m * WINN + j];
            acc0 += pr[j] * wv;
            acc1 += pr[PLANE + j] * wv;
            acc2 += pr[2 * PLANE + j] * wv;
            acc3 += pr[3 * PLANE + j] * wv;
        }
    }

    const size_t sidx = (size_t)n * KK * PIX + p;
    const float s0 = seg[sidx];
    const float s1 = seg[sidx + PIX];
    const float s2 = seg[sidx + 2 * (size_t)PIX];
    const float s3 = seg[sidx + 3 * (size_t)PIX];
    const float sw = swgt[(size_t)n * PIX + p];

    float vals[8] = { acc0 * s0, acc1 * s1, acc2 * s2, acc3 * s3,
                      sw * s0,   sw * s1,   sw * s2,   sw * s3 };

    __shared__ float lred[4][8];
    const int lane = tid & 63;
    const int wv_  = tid >> 6;
#pragma unroll
    for (int i = 0; i < 8; ++i) {
        float v = vals[i];
#pragma unroll
        for (int off = 32; off > 0; off >>= 1) v += __shfl_down(v, off, 64);
        if (lane == 0) lred[wv_][i] = v;
    }
    __syncthreads();
    if (tid < 8) {
        part[(size_t)blk * 8 + tid] =
            lred[0][tid] + lred[1][tid] + lred[2][tid] + lred[3][tid];
    }
}

__global__ __launch_bounds__(TPB) void ncuts_stage2(
    const float* __restrict__ part, float* __restrict__ out)
{
    const int n   = blockIdx.x;
    const int tid = threadIdx.x;

    float vals[8] = {0.f, 0.f, 0.f, 0.f, 0.f, 0.f, 0.f, 0.f};
    for (int b = tid; b < BPI; b += TPB) {
        const float* q = part + ((size_t)(n * BPI + b)) * 8;
#pragma unroll
        for (int i = 0; i < 8; ++i) vals[i] += q[i];
    }

    __shared__ float lred[4][8];
    const int lane = tid & 63;
    const int wv_  = tid >> 6;
#pragma unroll
    for (int i = 0; i < 8; ++i) {
        float v = vals[i];
#pragma unroll
        for (int off = 32; off > 0; off >>= 1) v += __shfl_down(v, off, 64);
        if (lane == 0) lred[wv_][i] = v;
    }
    __syncthreads();
    if (tid == 0) {
        float assoc = 0.f;
#pragma unroll
        for (int k = 0; k < 4; ++k) {
            const float A = lred[0][k] + lred[1][k] + lred[2][k] + lred[3][k];
            const float V = lred[0][4 + k] + lred[1][4 + k] + lred[2][4 + k] + lred[3][4 + k];
            assoc += A / V;
        }
        out[n] = 4.0f - assoc;
    }
}

extern "C" void kernel_launch(void* const* d_in, const int* in_sizes, int n_in,
                              void* d_out, int out_size, void* d_ws, size_t ws_size,
                              hipStream_t stream) {
    const float* seg  = (const float*)d_in[0];
    const float* pseg = (const float*)d_in[1];
    const float* wgt  = (const float*)d_in[2];
    const float* swgt = (const float*)d_in[3];
    float* out  = (float*)d_out;
    float* part = (float*)d_ws;   // 1568 blocks * 8 floats = 50176 B

    ncuts_stage1<<<NN * BPI, TPB, 0, stream>>>(seg, pseg, wgt, swgt, part);
    ncuts_stage2<<<NN, TPB, 0, stream>>>(part, out);
}